// Round 4
// baseline (1363.549 us; speedup 1.0000x reference)
//
#include <hip/hip_runtime.h>
#include <math.h>

#define HID 64
#define INC 256
#define LN_EPS 1e-5f
#define ALPHA 0.1f
#define NBKT 256     // max buckets (N<=131072); actual = ceil(N/512)
#define BCAP 12288   // per-bucket capacity; E/N*512 = 8192 expected, +45 sigma margin

typedef unsigned short ushort_t;
typedef unsigned int uint_t;
using short8v = __attribute__((ext_vector_type(8))) short;
using float4v = __attribute__((ext_vector_type(4))) float;

__device__ __forceinline__ float gelu_exact(float x) {
    return 0.5f * x * (1.0f + erff(x * 0.70710678118654752f));
}

__device__ __forceinline__ float wave_sum64(float v) {
#pragma unroll
    for (int m = 1; m < 64; m <<= 1) v += __shfl_xor(v, m, 64);
    return v;
}

__device__ __forceinline__ ushort_t f2bf(float f) {
    uint_t u = __float_as_uint(f);
    return (ushort_t)((u + 0x7fffu + ((u >> 16) & 1u)) >> 16);
}
__device__ __forceinline__ float bf_lo(uint_t v) { return __uint_as_float(v << 16); }
__device__ __forceinline__ float bf_hi(uint_t v) { return __uint_as_float(v & 0xffff0000u); }

__device__ __forceinline__ void split_bf(float f, ushort_t& hi, ushort_t& lo) {
    uint_t ub = __float_as_uint(f);
    uint_t h = (ub + 0x7fffu + ((ub >> 16) & 1u)) >> 16;
    hi = (ushort_t)h;
    float fl = f - __uint_as_float(h << 16);
    uint_t lb = __float_as_uint(fl);
    lo = (ushort_t)((lb + 0x7fffu + ((lb >> 16) & 1u)) >> 16);
}

// ---------- prep: W1 [256][64] f32 -> swizzled W^T bf16 hi/lo [64][256] ----------
__global__ __launch_bounds__(256) void k_prepW(const float* __restrict__ W1,
                                               ushort_t* __restrict__ whi,
                                               ushort_t* __restrict__ wlo) {
    int e = blockIdx.x * 256 + threadIdx.x;  // 16384 total
    int col = e & 63, k = e >> 6;
    float f = W1[(size_t)k * HID + col];
    ushort_t hi, lo;
    split_bf(f, hi, lo);
    int idx = col * 256 + (((k >> 3) ^ (col & 7)) << 3) + (k & 7);
    whi[idx] = hi;
    wlo[idx] = lo;
}

// ---------- bin edges by dst>>9; packed record = src | (localnode<<20) ----------
__global__ __launch_bounds__(256) void k_bin(const int* __restrict__ ei,
                                             int* __restrict__ bcur,
                                             uint_t* __restrict__ binned, int E) {
    __shared__ int hist[NBKT];
    __shared__ int base[NBKT];
    const int t = threadIdx.x;
    const int c0 = blockIdx.x * 4096;
    hist[t] = 0;
    __syncthreads();
#pragma unroll
    for (int i = 0; i < 16; ++i) {
        int e = c0 + i * 256 + t;
        if (e < E) atomicAdd(&hist[ei[E + e] >> 9], 1);
    }
    __syncthreads();
    {
        int h = hist[t];
        base[t] = (h > 0) ? atomicAdd(&bcur[t], h) : 0;
        hist[t] = 0;  // reuse as local rank cursor
    }
    __syncthreads();
#pragma unroll
    for (int i = 0; i < 16; ++i) {
        int e = c0 + i * 256 + t;
        if (e < E) {
            int src = ei[e];
            int dst = ei[E + e];
            int b = dst >> 9;
            int r = atomicAdd(&hist[b], 1);
            int pos = base[b] + r;
            if (pos >= BCAP) pos = BCAP - 1;  // safety clamp
            binned[(size_t)b * BCAP + pos] = (uint_t)src | ((uint_t)(dst & 511) << 20);
        }
    }
}

// ---------- scan bucket totals -> bucket bases; set rowstart[N]=E ----------
__global__ __launch_bounds__(256) void k_bktscan(const int* __restrict__ bcur,
                                                 int* __restrict__ bbase,
                                                 int* __restrict__ rowstart, int N, int E) {
    __shared__ int s[256];
    const int t = threadIdx.x;
    const int v = bcur[t];
    s[t] = v;
    __syncthreads();
#pragma unroll
    for (int off = 1; off < 256; off <<= 1) {
        int add = (t >= off) ? s[t - off] : 0;
        __syncthreads();
        s[t] += add;
        __syncthreads();
    }
    bbase[t] = s[t] - v;
    if (t == 0) rowstart[N] = E;
}

// ---------- per-bucket CSR: cnt, dinv, rowstart, scatter src ----------
__global__ __launch_bounds__(256) void k_csr(const uint_t* __restrict__ binned,
                                             const int* __restrict__ bcur,
                                             const int* __restrict__ bbase,
                                             int* __restrict__ csr,
                                             int* __restrict__ cnt,
                                             float* __restrict__ dinv,
                                             int* __restrict__ rowstart, int N) {
    __shared__ int cl[512];
    __shared__ int off[512];
    __shared__ int ps[256];
    const int b = blockIdx.x, t = threadIdx.x;
    const int nE = bcur[b];
    const int gbase = bbase[b];
    const uint_t* be = binned + (size_t)b * BCAP;
    cl[t] = 0;
    cl[t + 256] = 0;
    __syncthreads();
    for (int i = t; i < nE; i += 256) atomicAdd(&cl[be[i] >> 20], 1);
    __syncthreads();
    const int pa = cl[2 * t], pb_ = cl[2 * t + 1];
    const int p = pa + pb_;
    ps[t] = p;
    __syncthreads();
#pragma unroll
    for (int o = 1; o < 256; o <<= 1) {
        int add = (t >= o) ? ps[t - o] : 0;
        __syncthreads();
        ps[t] += add;
        __syncthreads();
    }
    const int pbase = ps[t] - p;
    off[2 * t] = pbase;
    off[2 * t + 1] = pbase + pa;
    __syncthreads();
    const int n0 = b * 512;
    for (int i = t; i < 512; i += 256) {
        int g = n0 + i;
        if (g < N) {
            int c = cl[i];
            cnt[g] = c;
            dinv[g] = rsqrtf((float)(c + 1));
            rowstart[g] = gbase + off[i];
        }
    }
    __syncthreads();
    for (int i = t; i < nE; i += 256) {
        uint_t rec = be[i];
        int ln = rec >> 20;
        int r = atomicAdd(&off[ln], 1);
        csr[gbase + r] = (int)(rec & 0xFFFFFu);
    }
}

// ---------- GEMM1 (MFMA) + gelu + LN fused: u0 = dinv * LN(gelu(x @ W1 + b1)) ----------
// u0 written in 4-shard layout: shard s (=ct) holds features [16s,16s+16) for all nodes.
__global__ __launch_bounds__(256) void k_gemm1ln(const float* __restrict__ x,
                                                 const ushort_t* __restrict__ whi,
                                                 const ushort_t* __restrict__ wlo,
                                                 const float* __restrict__ b1,
                                                 const float* __restrict__ g1,
                                                 const float* __restrict__ be1,
                                                 const float* __restrict__ dinv,
                                                 ushort_t* __restrict__ u0, int N) {
    __shared__ ushort_t Wh[16384];
    __shared__ ushort_t Wl[16384];
    const int t = threadIdx.x;
    {
        const uint4* s1 = (const uint4*)whi;
        uint4* d1 = (uint4*)Wh;
        for (int i = t; i < 2048; i += 256) d1[i] = s1[i];
        const uint4* s2 = (const uint4*)wlo;
        uint4* d2 = (uint4*)Wl;
        for (int i = t; i < 2048; i += 256) d2[i] = s2[i];
    }
    __syncthreads();

    const int lane = t & 63, w = t >> 6;
    const int l15 = lane & 15, lg = lane >> 4;
    const int row0 = blockIdx.x * 64 + w * 16;
    int rowc = row0 + l15;
    if (rowc > N - 1) rowc = N - 1;
    const float* xr = x + (size_t)rowc * INC + lg * 8;

    float4 A0 = *(const float4*)(xr);
    float4 A1 = *(const float4*)(xr + 4);
    float4v acc[4];
#pragma unroll
    for (int i = 0; i < 4; ++i) acc[i] = (float4v){0.f, 0.f, 0.f, 0.f};

    union U8 { short8v v; ushort_t u[8]; };

#pragma unroll
    for (int t8 = 0; t8 < 8; ++t8) {
        float4 P0, P1;
        if (t8 < 7) {
            P0 = *(const float4*)(xr + (t8 + 1) * 32);
            P1 = *(const float4*)(xr + (t8 + 1) * 32 + 4);
        }
        U8 ahi, alo;
        {
            const float af[8] = {A0.x, A0.y, A0.z, A0.w, A1.x, A1.y, A1.z, A1.w};
#pragma unroll
            for (int j = 0; j < 8; ++j) split_bf(af[j], ahi.u[j], alo.u[j]);
        }
#pragma unroll
        for (int ct = 0; ct < 4; ++ct) {
            const int col = ct * 16 + l15;
            const int kb = t8 * 4 + lg;
            const int idx = col * 256 + ((kb ^ (col & 7)) << 3);
            short8v bhi = *(const short8v*)&Wh[idx];
            short8v blo = *(const short8v*)&Wl[idx];
            acc[ct] = __builtin_amdgcn_mfma_f32_16x16x32_bf16(ahi.v, bhi, acc[ct], 0, 0, 0);
            acc[ct] = __builtin_amdgcn_mfma_f32_16x16x32_bf16(ahi.v, blo, acc[ct], 0, 0, 0);
            acc[ct] = __builtin_amdgcn_mfma_f32_16x16x32_bf16(alo.v, bhi, acc[ct], 0, 0, 0);
        }
        if (t8 < 7) { A0 = P0; A1 = P1; }
    }

    float b1c[4], g1c[4], bec[4];
#pragma unroll
    for (int ct = 0; ct < 4; ++ct) {
        const int col = ct * 16 + l15;
        b1c[ct] = b1[col];
        g1c[ct] = g1[col];
        bec[ct] = be1[col];
    }
    float gv[4][4];
#pragma unroll
    for (int ct = 0; ct < 4; ++ct)
#pragma unroll
        for (int r = 0; r < 4; ++r) gv[ct][r] = gelu_exact(acc[ct][r] + b1c[ct]);

    float mu[4], rsv[4];
#pragma unroll
    for (int r = 0; r < 4; ++r) {
        float p = gv[0][r] + gv[1][r] + gv[2][r] + gv[3][r];
        p += __shfl_xor(p, 1, 64);
        p += __shfl_xor(p, 2, 64);
        p += __shfl_xor(p, 4, 64);
        p += __shfl_xor(p, 8, 64);
        mu[r] = p * (1.0f / 64.0f);
        float d0 = gv[0][r] - mu[r], d1 = gv[1][r] - mu[r];
        float d2 = gv[2][r] - mu[r], d3 = gv[3][r] - mu[r];
        float p2 = d0 * d0 + d1 * d1 + d2 * d2 + d3 * d3;
        p2 += __shfl_xor(p2, 1, 64);
        p2 += __shfl_xor(p2, 2, 64);
        p2 += __shfl_xor(p2, 4, 64);
        p2 += __shfl_xor(p2, 8, 64);
        rsv[r] = rsqrtf(p2 * (1.0f / 64.0f) + LN_EPS);
    }
#pragma unroll
    for (int r = 0; r < 4; ++r) {
        const int row = row0 + lg * 4 + r;
        if (row < N) {
            const float di = dinv[row];
#pragma unroll
            for (int ct = 0; ct < 4; ++ct) {
                const float ln = (gv[ct][r] - mu[r]) * rsv[r] * g1c[ct] + bec[ct];
                u0[(size_t)ct * N * 16 + (size_t)row * 16 + l15] = f2bf(di * ln);
            }
        }
    }
}

// ---------- APPNP step, feature-sharded + XCD-affine ----------
// u' = (1-a)*dinv^2*(sum_adj u + u[self]) + a*u0, per 16-feature shard.
// blockIdx%8 = XCD (empirical); shard s -> XCDs {2s,2s+1}: per-XCD gather
// footprint = 3.2MB (fits 4MB L2). Wave per node; 16 edge-slots x 4 lanes (uint2).
__global__ __launch_bounds__(256) void k_prop(const ushort_t* __restrict__ uin,
                                              const ushort_t* __restrict__ u0,
                                              ushort_t* __restrict__ uout,
                                              const int* __restrict__ csr,
                                              const int* __restrict__ rowstart,
                                              const float* __restrict__ dinv,
                                              int N, int nbNodeBlocks) {
    const int blk = blockIdx.x;
    const int g = blk & 7;
    const int shard = g >> 1;
    const int nb = ((blk >> 3) << 1) + (g & 1);
    if (nb >= nbNodeBlocks) return;
    const int node = nb * 4 + (threadIdx.x >> 6);
    if (node >= N) return;
    const int lane = threadIdx.x & 63;
    const int es = lane >> 2, fl = lane & 3;
    const uint2* U = (const uint2*)uin + (size_t)shard * N * 4;
    const int s0 = rowstart[node];
    const int e1 = rowstart[node + 1];
    float a0 = 0.f, a1 = 0.f, a2 = 0.f, a3 = 0.f;
    for (int e = s0; e < e1; e += 16) {
        const int i = e + es;
        const bool ok = i < e1;
        const int src = csr[ok ? i : s0];
        const uint2 v = U[(size_t)src * 4 + fl];
        const float f = ok ? 1.0f : 0.0f;
        a0 = fmaf(f, bf_lo(v.x), a0);
        a1 = fmaf(f, bf_hi(v.x), a1);
        a2 = fmaf(f, bf_lo(v.y), a2);
        a3 = fmaf(f, bf_hi(v.y), a3);
    }
#pragma unroll
    for (int m = 4; m < 64; m <<= 1) {
        a0 += __shfl_xor(a0, m, 64);
        a1 += __shfl_xor(a1, m, 64);
        a2 += __shfl_xor(a2, m, 64);
        a3 += __shfl_xor(a3, m, 64);
    }
    if (lane < 4) {
        const uint2 ud = U[(size_t)node * 4 + fl];
        const uint2 uz = ((const uint2*)u0 + (size_t)shard * N * 4)[(size_t)node * 4 + fl];
        const float di = dinv[node];
        const float c = (1.0f - ALPHA) * di * di;
        const float r0 = c * (a0 + bf_lo(ud.x)) + ALPHA * bf_lo(uz.x);
        const float r1 = c * (a1 + bf_hi(ud.x)) + ALPHA * bf_hi(uz.x);
        const float r2 = c * (a2 + bf_lo(ud.y)) + ALPHA * bf_lo(uz.y);
        const float r3 = c * (a3 + bf_hi(ud.y)) + ALPHA * bf_hi(uz.y);
        uint2 o;
        o.x = (uint_t)f2bf(r0) | ((uint_t)f2bf(r1) << 16);
        o.y = (uint_t)f2bf(r2) | ((uint_t)f2bf(r3) << 16);
        ((uint2*)uout + (size_t)shard * N * 4)[(size_t)node * 4 + fl] = o;
    }
}

// ---------- final: out = LN(gelu(u/dinv)) @ W2 + b2 (shard-layout u) ----------
__global__ __launch_bounds__(256) void k_final(const ushort_t* __restrict__ u,
                                               const int* __restrict__ cnt,
                                               const float* __restrict__ g2,
                                               const float* __restrict__ be2,
                                               const float* __restrict__ W2,
                                               const float* __restrict__ b2,
                                               float* __restrict__ out, int N) {
    const int lane = threadIdx.x & 63;
    const int wid = threadIdx.x >> 6;
    const int gw = blockIdx.x * 4 + wid;
    const int nw = gridDim.x * 4;
    const size_t shoff = (size_t)(lane >> 4) * N * 16 + (lane & 15);
    float w2r[64];
#pragma unroll
    for (int k = 0; k < 64; ++k) w2r[k] = W2[k * HID + lane];
    const float bb = b2[lane];
    const float gg = g2[lane];
    const float bt = be2[lane];
    for (int row = gw; row < N; row += nw) {
        const float sc = sqrtf((float)(cnt[row] + 1));  // 1/dinv
        float v = gelu_exact(__uint_as_float((uint_t)u[shoff + (size_t)row * 16] << 16) * sc);
        const float mu = wave_sum64(v) * (1.0f / 64.0f);
        const float d = v - mu;
        const float var = wave_sum64(d * d) * (1.0f / 64.0f);
        const float vn = d * rsqrtf(var + LN_EPS) * gg + bt;
        float acc = bb;
#pragma unroll
        for (int k = 0; k < 64; ++k) acc += __shfl(vn, k, 64) * w2r[k];
        out[(size_t)row * HID + lane] = acc;
    }
}

extern "C" void kernel_launch(void* const* d_in, const int* in_sizes, int n_in,
                              void* d_out, int out_size, void* d_ws, size_t ws_size,
                              hipStream_t stream) {
    const float* x   = (const float*)d_in[0];
    const int*   ei  = (const int*)d_in[1];
    const float* W1  = (const float*)d_in[2];
    const float* b1  = (const float*)d_in[3];
    const float* g1  = (const float*)d_in[4];
    const float* be1 = (const float*)d_in[5];
    const float* g2  = (const float*)d_in[6];
    const float* be2 = (const float*)d_in[7];
    const float* W2  = (const float*)d_in[8];
    const float* b2  = (const float*)d_in[9];
    float* out = (float*)d_out;

    const int N = in_sizes[0] / INC;
    const int E = in_sizes[1] / 2;

    char* ws = (char*)d_ws;
    size_t o = 0;
    auto alloc = [&](size_t bytes) { size_t r = o; o += (bytes + 255) & ~(size_t)255; return r; };
    ushort_t* u0 = (ushort_t*)(ws + alloc((size_t)N * HID * 2));
    ushort_t* ua = (ushort_t*)(ws + alloc((size_t)N * HID * 2));
    ushort_t* ub = (ushort_t*)(ws + alloc((size_t)N * HID * 2));
    float* dinv     = (float*)(ws + alloc((size_t)N * 4));
    int*   cnt      = (int*)(ws + alloc((size_t)N * 4));
    int*   rowstart = (int*)(ws + alloc((size_t)(N + 1) * 4));
    int*   bcur     = (int*)(ws + alloc(NBKT * 4));
    int*   bbase    = (int*)(ws + alloc(NBKT * 4));
    ushort_t* whi   = (ushort_t*)(ws + alloc(16384 * 2));
    ushort_t* wlo   = (ushort_t*)(ws + alloc(16384 * 2));
    uint_t* binned  = (uint_t*)(ws + alloc((size_t)NBKT * BCAP * 4));
    int*   csr      = (int*)(ws + alloc((size_t)E * 4));

    const int nbkt = (N + 511) / 512;  // 196 for N=100000 (<= NBKT)
    const int nbNodeBlocks = (N + 3) / 4;
    const int propGrid = 8 * ((nbNodeBlocks + 1) / 2);

    hipMemsetAsync(bcur, 0, NBKT * 4, stream);
    k_prepW<<<64, 256, 0, stream>>>(W1, whi, wlo);
    k_bin<<<(E + 4095) / 4096, 256, 0, stream>>>(ei, bcur, binned, E);
    k_bktscan<<<1, 256, 0, stream>>>(bcur, bbase, rowstart, N, E);
    k_csr<<<nbkt, 256, 0, stream>>>(binned, bcur, bbase, csr, cnt, dinv, rowstart, N);
    k_gemm1ln<<<(N + 63) / 64, 256, 0, stream>>>(x, whi, wlo, b1, g1, be1, dinv, u0, N);

    ushort_t* bufs[2] = {ua, ub};
    const ushort_t* pin = u0;
    for (int k = 0; k < 10; ++k) {
        ushort_t* pout = bufs[k & 1];
        k_prop<<<propGrid, 256, 0, stream>>>(pin, u0, pout, csr, rowstart, dinv, N, nbNodeBlocks);
        pin = pout;
    }
    k_final<<<1024, 256, 0, stream>>>(pin, cnt, g2, be2, W2, b2, out, N);
}

// Round 5
// 527.408 us; speedup vs baseline: 2.5854x; 2.5854x over previous
//
#include <hip/hip_runtime.h>
#include <math.h>

#define HID 64
#define INC 256
#define LN_EPS 1e-5f
#define ALPHA 0.1f
#define NBKT 256     // max buckets (N<=131072); actual = ceil(N/512)
#define BCAP 12288   // per-bucket capacity; E/N*512 = 8192 expected, +45 sigma margin

typedef unsigned short ushort_t;
typedef unsigned int uint_t;
using short8v = __attribute__((ext_vector_type(8))) short;
using float4v = __attribute__((ext_vector_type(4))) float;

__device__ __forceinline__ float gelu_exact(float x) {
    return 0.5f * x * (1.0f + erff(x * 0.70710678118654752f));
}

__device__ __forceinline__ float wave_sum64(float v) {
#pragma unroll
    for (int m = 1; m < 64; m <<= 1) v += __shfl_xor(v, m, 64);
    return v;
}

__device__ __forceinline__ ushort_t f2bf(float f) {
    uint_t u = __float_as_uint(f);
    return (ushort_t)((u + 0x7fffu + ((u >> 16) & 1u)) >> 16);
}
__device__ __forceinline__ float bf_lo(uint_t v) { return __uint_as_float(v << 16); }
__device__ __forceinline__ float bf_hi(uint_t v) { return __uint_as_float(v & 0xffff0000u); }

__device__ __forceinline__ void split_bf(float f, ushort_t& hi, ushort_t& lo) {
    uint_t ub = __float_as_uint(f);
    uint_t h = (ub + 0x7fffu + ((ub >> 16) & 1u)) >> 16;
    hi = (ushort_t)h;
    float fl = f - __uint_as_float(h << 16);
    uint_t lb = __float_as_uint(fl);
    lo = (ushort_t)((lb + 0x7fffu + ((lb >> 16) & 1u)) >> 16);
}

// ---------- prep: W1 [256][64] f32 -> swizzled W^T bf16 hi/lo [64][256] ----------
// element (col,k) at col*256 + ((k>>3)^(col&7))*8 + (k&7)
__global__ __launch_bounds__(256) void k_prepW(const float* __restrict__ W1,
                                               ushort_t* __restrict__ whi,
                                               ushort_t* __restrict__ wlo) {
    int e = blockIdx.x * 256 + threadIdx.x;  // 16384 total
    int col = e & 63, k = e >> 6;
    float f = W1[(size_t)k * HID + col];
    ushort_t hi, lo;
    split_bf(f, hi, lo);
    int idx = col * 256 + (((k >> 3) ^ (col & 7)) << 3) + (k & 7);
    whi[idx] = hi;
    wlo[idx] = lo;
}

// ---------- prep: W2 [64][64] f32 -> swizzled W^T bf16 hi/lo [64][64] ----------
__global__ __launch_bounds__(256) void k_prepW2(const float* __restrict__ W2,
                                                ushort_t* __restrict__ whi,
                                                ushort_t* __restrict__ wlo) {
    int e = blockIdx.x * 256 + threadIdx.x;  // 4096 total
    int col = e & 63, k = e >> 6;
    float f = W2[(size_t)k * HID + col];
    ushort_t hi, lo;
    split_bf(f, hi, lo);
    int idx = col * 64 + (((k >> 3) ^ (col & 7)) << 3) + (k & 7);
    whi[idx] = hi;
    wlo[idx] = lo;
}

// ---------- bin edges by dst>>9; packed record = src | (localnode<<20) ----------
__global__ __launch_bounds__(256) void k_bin(const int* __restrict__ ei,
                                             int* __restrict__ bcur,
                                             uint_t* __restrict__ binned, int E) {
    __shared__ int hist[NBKT];
    __shared__ int base[NBKT];
    const int t = threadIdx.x;
    const int c0 = blockIdx.x * 4096;
    hist[t] = 0;
    __syncthreads();
#pragma unroll
    for (int i = 0; i < 16; ++i) {
        int e = c0 + i * 256 + t;
        if (e < E) atomicAdd(&hist[ei[E + e] >> 9], 1);
    }
    __syncthreads();
    {
        int h = hist[t];
        base[t] = (h > 0) ? atomicAdd(&bcur[t], h) : 0;
        hist[t] = 0;  // reuse as local rank cursor
    }
    __syncthreads();
#pragma unroll
    for (int i = 0; i < 16; ++i) {
        int e = c0 + i * 256 + t;
        if (e < E) {
            int src = ei[e];
            int dst = ei[E + e];
            int b = dst >> 9;
            int r = atomicAdd(&hist[b], 1);
            int pos = base[b] + r;
            if (pos >= BCAP) pos = BCAP - 1;  // safety clamp
            binned[(size_t)b * BCAP + pos] = (uint_t)src | ((uint_t)(dst & 511) << 20);
        }
    }
}

// ---------- scan bucket totals -> bucket bases; set rowstart[N]=E ----------
__global__ __launch_bounds__(256) void k_bktscan(const int* __restrict__ bcur,
                                                 int* __restrict__ bbase,
                                                 int* __restrict__ rowstart, int N, int E) {
    __shared__ int s[256];
    const int t = threadIdx.x;
    const int v = bcur[t];
    s[t] = v;
    __syncthreads();
#pragma unroll
    for (int off = 1; off < 256; off <<= 1) {
        int add = (t >= off) ? s[t - off] : 0;
        __syncthreads();
        s[t] += add;
        __syncthreads();
    }
    bbase[t] = s[t] - v;
    if (t == 0) rowstart[N] = E;
}

// ---------- per-bucket CSR: cnt, dinv, rowstart, scatter src ----------
__global__ __launch_bounds__(256) void k_csr(const uint_t* __restrict__ binned,
                                             const int* __restrict__ bcur,
                                             const int* __restrict__ bbase,
                                             int* __restrict__ csr,
                                             int* __restrict__ cnt,
                                             float* __restrict__ dinv,
                                             int* __restrict__ rowstart, int N) {
    __shared__ int cl[512];
    __shared__ int off[512];
    __shared__ int ps[256];
    const int b = blockIdx.x, t = threadIdx.x;
    const int nE = bcur[b];
    const int gbase = bbase[b];
    const uint_t* be = binned + (size_t)b * BCAP;
    cl[t] = 0;
    cl[t + 256] = 0;
    __syncthreads();
    for (int i = t; i < nE; i += 256) atomicAdd(&cl[be[i] >> 20], 1);
    __syncthreads();
    const int pa = cl[2 * t], pb_ = cl[2 * t + 1];
    const int p = pa + pb_;
    ps[t] = p;
    __syncthreads();
#pragma unroll
    for (int o = 1; o < 256; o <<= 1) {
        int add = (t >= o) ? ps[t - o] : 0;
        __syncthreads();
        ps[t] += add;
        __syncthreads();
    }
    const int pbase = ps[t] - p;
    off[2 * t] = pbase;
    off[2 * t + 1] = pbase + pa;
    __syncthreads();
    const int n0 = b * 512;
    for (int i = t; i < 512; i += 256) {
        int g = n0 + i;
        if (g < N) {
            int c = cl[i];
            cnt[g] = c;
            dinv[g] = rsqrtf((float)(c + 1));
            rowstart[g] = gbase + off[i];
        }
    }
    __syncthreads();
    for (int i = t; i < nE; i += 256) {
        uint_t rec = be[i];
        int ln = rec >> 20;
        int r = atomicAdd(&off[ln], 1);
        csr[gbase + r] = (int)(rec & 0xFFFFFu);
    }
}

// ---------- GEMM1 (MFMA) + gelu + LN fused: u0 = dinv * LN(gelu(x @ W1 + b1)) ----------
// u0 row-major [N][64] bf16.
__global__ __launch_bounds__(256) void k_gemm1ln(const float* __restrict__ x,
                                                 const ushort_t* __restrict__ whi,
                                                 const ushort_t* __restrict__ wlo,
                                                 const float* __restrict__ b1,
                                                 const float* __restrict__ g1,
                                                 const float* __restrict__ be1,
                                                 const float* __restrict__ dinv,
                                                 ushort_t* __restrict__ u0, int N) {
    __shared__ ushort_t Wh[16384];
    __shared__ ushort_t Wl[16384];
    const int t = threadIdx.x;
    {
        const uint4* s1 = (const uint4*)whi;
        uint4* d1 = (uint4*)Wh;
        for (int i = t; i < 2048; i += 256) d1[i] = s1[i];
        const uint4* s2 = (const uint4*)wlo;
        uint4* d2 = (uint4*)Wl;
        for (int i = t; i < 2048; i += 256) d2[i] = s2[i];
    }
    __syncthreads();

    const int lane = t & 63, w = t >> 6;
    const int l15 = lane & 15, lg = lane >> 4;
    const int row0 = blockIdx.x * 64 + w * 16;
    int rowc = row0 + l15;
    if (rowc > N - 1) rowc = N - 1;
    const float* xr = x + (size_t)rowc * INC + lg * 8;

    float4 A0 = *(const float4*)(xr);
    float4 A1 = *(const float4*)(xr + 4);
    float4v acc[4];
#pragma unroll
    for (int i = 0; i < 4; ++i) acc[i] = (float4v){0.f, 0.f, 0.f, 0.f};

    union U8 { short8v v; ushort_t u[8]; };

#pragma unroll
    for (int t8 = 0; t8 < 8; ++t8) {
        float4 P0, P1;
        if (t8 < 7) {
            P0 = *(const float4*)(xr + (t8 + 1) * 32);
            P1 = *(const float4*)(xr + (t8 + 1) * 32 + 4);
        }
        U8 ahi, alo;
        {
            const float af[8] = {A0.x, A0.y, A0.z, A0.w, A1.x, A1.y, A1.z, A1.w};
#pragma unroll
            for (int j = 0; j < 8; ++j) split_bf(af[j], ahi.u[j], alo.u[j]);
        }
#pragma unroll
        for (int ct = 0; ct < 4; ++ct) {
            const int col = ct * 16 + l15;
            const int kb = t8 * 4 + lg;
            const int idx = col * 256 + ((kb ^ (col & 7)) << 3);
            short8v bhi = *(const short8v*)&Wh[idx];
            short8v blo = *(const short8v*)&Wl[idx];
            acc[ct] = __builtin_amdgcn_mfma_f32_16x16x32_bf16(ahi.v, bhi, acc[ct], 0, 0, 0);
            acc[ct] = __builtin_amdgcn_mfma_f32_16x16x32_bf16(ahi.v, blo, acc[ct], 0, 0, 0);
            acc[ct] = __builtin_amdgcn_mfma_f32_16x16x32_bf16(alo.v, bhi, acc[ct], 0, 0, 0);
        }
        if (t8 < 7) { A0 = P0; A1 = P1; }
    }

    float b1c[4], g1c[4], bec[4];
#pragma unroll
    for (int ct = 0; ct < 4; ++ct) {
        const int col = ct * 16 + l15;
        b1c[ct] = b1[col];
        g1c[ct] = g1[col];
        bec[ct] = be1[col];
    }
    float gv[4][4];
#pragma unroll
    for (int ct = 0; ct < 4; ++ct)
#pragma unroll
        for (int r = 0; r < 4; ++r) gv[ct][r] = gelu_exact(acc[ct][r] + b1c[ct]);

    float mu[4], rsv[4];
#pragma unroll
    for (int r = 0; r < 4; ++r) {
        float p = gv[0][r] + gv[1][r] + gv[2][r] + gv[3][r];
        p += __shfl_xor(p, 1, 64);
        p += __shfl_xor(p, 2, 64);
        p += __shfl_xor(p, 4, 64);
        p += __shfl_xor(p, 8, 64);
        mu[r] = p * (1.0f / 64.0f);
        float d0 = gv[0][r] - mu[r], d1 = gv[1][r] - mu[r];
        float d2 = gv[2][r] - mu[r], d3 = gv[3][r] - mu[r];
        float p2 = d0 * d0 + d1 * d1 + d2 * d2 + d3 * d3;
        p2 += __shfl_xor(p2, 1, 64);
        p2 += __shfl_xor(p2, 2, 64);
        p2 += __shfl_xor(p2, 4, 64);
        p2 += __shfl_xor(p2, 8, 64);
        rsv[r] = rsqrtf(p2 * (1.0f / 64.0f) + LN_EPS);
    }
#pragma unroll
    for (int r = 0; r < 4; ++r) {
        const int row = row0 + lg * 4 + r;
        if (row < N) {
            const float di = dinv[row];
#pragma unroll
            for (int ct = 0; ct < 4; ++ct) {
                const float ln = (gv[ct][r] - mu[r]) * rsv[r] * g1c[ct] + bec[ct];
                u0[(size_t)row * HID + ct * 16 + l15] = f2bf(di * ln);
            }
        }
    }
}

// ---------- APPNP step in u-space: u' = (1-a)*dinv^2*(sum_adj u + u[self]) + a*u0 ------
// wave per node; quarter-wave (16 lanes) per edge, uint2 (4 bf16)/lane; 16 edges in flight.
__global__ __launch_bounds__(256) void k_prop(const ushort_t* __restrict__ uin,
                                              const ushort_t* __restrict__ u0,
                                              ushort_t* __restrict__ uout,
                                              const int* __restrict__ csr,
                                              const int* __restrict__ rowstart,
                                              const float* __restrict__ dinv, int N) {
    const int t = threadIdx.x;
    const int lane = t & 63;
    const int q = lane >> 4, fl = lane & 15;
    const int node = blockIdx.x * 4 + (t >> 6);
    if (node >= N) return;
    const uint2* U = (const uint2*)uin;
    const int s0 = rowstart[node];
    const int e1 = rowstart[node + 1];
    float a0 = 0.f, a1 = 0.f, a2 = 0.f, a3 = 0.f;
    for (int e = s0; e < e1; e += 16) {
        int idx[4];
        bool ok[4];
#pragma unroll
        for (int b = 0; b < 4; ++b) {
            const int i = e + b * 4 + q;
            ok[b] = i < e1;
            idx[b] = csr[ok[b] ? i : s0];
        }
        uint2 v[4];
#pragma unroll
        for (int b = 0; b < 4; ++b) v[b] = U[(size_t)idx[b] * 16 + fl];
#pragma unroll
        for (int b = 0; b < 4; ++b) {
            const float f = ok[b] ? 1.0f : 0.0f;
            a0 = fmaf(f, bf_lo(v[b].x), a0);
            a1 = fmaf(f, bf_hi(v[b].x), a1);
            a2 = fmaf(f, bf_lo(v[b].y), a2);
            a3 = fmaf(f, bf_hi(v[b].y), a3);
        }
    }
    a0 += __shfl_xor(a0, 16, 64); a0 += __shfl_xor(a0, 32, 64);
    a1 += __shfl_xor(a1, 16, 64); a1 += __shfl_xor(a1, 32, 64);
    a2 += __shfl_xor(a2, 16, 64); a2 += __shfl_xor(a2, 32, 64);
    a3 += __shfl_xor(a3, 16, 64); a3 += __shfl_xor(a3, 32, 64);
    if (lane < 16) {
        const uint2 ud = U[(size_t)node * 16 + fl];
        const uint2 uz = ((const uint2*)u0)[(size_t)node * 16 + fl];
        const float di = dinv[node];
        const float c = (1.0f - ALPHA) * di * di;
        const float r0 = c * (a0 + bf_lo(ud.x)) + ALPHA * bf_lo(uz.x);
        const float r1 = c * (a1 + bf_hi(ud.x)) + ALPHA * bf_hi(uz.x);
        const float r2 = c * (a2 + bf_lo(ud.y)) + ALPHA * bf_lo(uz.y);
        const float r3 = c * (a3 + bf_hi(ud.y)) + ALPHA * bf_hi(uz.y);
        uint2 o;
        o.x = (uint_t)f2bf(r0) | ((uint_t)f2bf(r1) << 16);
        o.y = (uint_t)f2bf(r2) | ((uint_t)f2bf(r3) << 16);
        ((uint2*)uout)[(size_t)node * 16 + fl] = o;
    }
}

// ---------- final (MFMA): out = LN(gelu(u/dinv)) @ W2 + b2 ----------
// wave -> 16 rows; lane l15 = row, lg*8(+32) = k-slices; 2 K-steps x 4 col-tiles x 2 terms.
__global__ __launch_bounds__(256) void k_final(const ushort_t* __restrict__ u,
                                               const int* __restrict__ cnt,
                                               const float* __restrict__ g2,
                                               const float* __restrict__ be2,
                                               const ushort_t* __restrict__ w2hi,
                                               const ushort_t* __restrict__ w2lo,
                                               const float* __restrict__ b2,
                                               float* __restrict__ out, int N) {
    __shared__ ushort_t Wh[4096];
    __shared__ ushort_t Wl[4096];
    const int t = threadIdx.x;
    {
        const uint4* s1 = (const uint4*)w2hi;
        uint4* d1 = (uint4*)Wh;
        for (int i = t; i < 512; i += 256) d1[i] = s1[i];
        const uint4* s2 = (const uint4*)w2lo;
        uint4* d2 = (uint4*)Wl;
        for (int i = t; i < 512; i += 256) d2[i] = s2[i];
    }
    __syncthreads();

    const int lane = t & 63, w = t >> 6;
    const int l15 = lane & 15, lg = lane >> 4;
    const int row0 = blockIdx.x * 64 + w * 16;
    if (row0 >= N) return;
    int rowc = row0 + l15;
    if (rowc > N - 1) rowc = N - 1;

    // load 16 features: k in [lg*8, lg*8+8) and [32+lg*8, 32+lg*8+8)
    const uint4 uva = *(const uint4*)(u + (size_t)rowc * HID + lg * 8);
    const uint4 uvb = *(const uint4*)(u + (size_t)rowc * HID + 32 + lg * 8);
    const float sc = sqrtf((float)(cnt[rowc] + 1));  // 1/dinv

    float v[16];
    {
        const uint_t ua_[4] = {uva.x, uva.y, uva.z, uva.w};
        const uint_t ub_[4] = {uvb.x, uvb.y, uvb.z, uvb.w};
#pragma unroll
        for (int j = 0; j < 4; ++j) {
            v[2 * j] = gelu_exact(bf_lo(ua_[j]) * sc);
            v[2 * j + 1] = gelu_exact(bf_hi(ua_[j]) * sc);
            v[8 + 2 * j] = gelu_exact(bf_lo(ub_[j]) * sc);
            v[8 + 2 * j + 1] = gelu_exact(bf_hi(ub_[j]) * sc);
        }
    }
    // LN over the row (4 lanes per row: reduce over lg via xor 16,32)
    float s = 0.f;
#pragma unroll
    for (int j = 0; j < 16; ++j) s += v[j];
    s += __shfl_xor(s, 16, 64);
    s += __shfl_xor(s, 32, 64);
    const float mu = s * (1.0f / 64.0f);
    float sq = 0.f;
#pragma unroll
    for (int j = 0; j < 16; ++j) {
        v[j] -= mu;
        sq += v[j] * v[j];
    }
    sq += __shfl_xor(sq, 16, 64);
    sq += __shfl_xor(sq, 32, 64);
    const float rs = rsqrtf(sq * (1.0f / 64.0f) + LN_EPS);

    union U8 { short8v v; ushort_t u[8]; };
    U8 a0, a1;
#pragma unroll
    for (int j = 0; j < 8; ++j) {
        const int ka = lg * 8 + j;
        const int kb = 32 + lg * 8 + j;
        a0.u[j] = f2bf(v[j] * rs * g2[ka] + be2[ka]);
        a1.u[j] = f2bf(v[8 + j] * rs * g2[kb] + be2[kb]);
    }

    float4v acc[4];
#pragma unroll
    for (int i = 0; i < 4; ++i) acc[i] = (float4v){0.f, 0.f, 0.f, 0.f};
#pragma unroll
    for (int ct = 0; ct < 4; ++ct) {
        const int col = ct * 16 + l15;
        const int i0 = col * 64 + ((lg ^ (col & 7)) << 3);
        const int i1 = col * 64 + (((4 + lg) ^ (col & 7)) << 3);
        short8v b0h = *(const short8v*)&Wh[i0];
        short8v b0l = *(const short8v*)&Wl[i0];
        short8v b1h = *(const short8v*)&Wh[i1];
        short8v b1l = *(const short8v*)&Wl[i1];
        acc[ct] = __builtin_amdgcn_mfma_f32_16x16x32_bf16(a0.v, b0h, acc[ct], 0, 0, 0);
        acc[ct] = __builtin_amdgcn_mfma_f32_16x16x32_bf16(a0.v, b0l, acc[ct], 0, 0, 0);
        acc[ct] = __builtin_amdgcn_mfma_f32_16x16x32_bf16(a1.v, b1h, acc[ct], 0, 0, 0);
        acc[ct] = __builtin_amdgcn_mfma_f32_16x16x32_bf16(a1.v, b1l, acc[ct], 0, 0, 0);
    }

#pragma unroll
    for (int ct = 0; ct < 4; ++ct) {
        const float bb = b2[ct * 16 + l15];
#pragma unroll
        for (int r = 0; r < 4; ++r) {
            const int row = row0 + lg * 4 + r;
            if (row < N) out[(size_t)row * HID + ct * 16 + l15] = acc[ct][r] + bb;
        }
    }
}

extern "C" void kernel_launch(void* const* d_in, const int* in_sizes, int n_in,
                              void* d_out, int out_size, void* d_ws, size_t ws_size,
                              hipStream_t stream) {
    const float* x   = (const float*)d_in[0];
    const int*   ei  = (const int*)d_in[1];
    const float* W1  = (const float*)d_in[2];
    const float* b1  = (const float*)d_in[3];
    const float* g1  = (const float*)d_in[4];
    const float* be1 = (const float*)d_in[5];
    const float* g2  = (const float*)d_in[6];
    const float* be2 = (const float*)d_in[7];
    const float* W2  = (const float*)d_in[8];
    const float* b2  = (const float*)d_in[9];
    float* out = (float*)d_out;

    const int N = in_sizes[0] / INC;
    const int E = in_sizes[1] / 2;

    char* ws = (char*)d_ws;
    size_t o = 0;
    auto alloc = [&](size_t bytes) { size_t r = o; o += (bytes + 255) & ~(size_t)255; return r; };
    ushort_t* u0 = (ushort_t*)(ws + alloc((size_t)N * HID * 2));
    ushort_t* ua = (ushort_t*)(ws + alloc((size_t)N * HID * 2));
    ushort_t* ub = (ushort_t*)(ws + alloc((size_t)N * HID * 2));
    float* dinv     = (float*)(ws + alloc((size_t)N * 4));
    int*   cnt      = (int*)(ws + alloc((size_t)N * 4));
    int*   rowstart = (int*)(ws + alloc((size_t)(N + 1) * 4));
    int*   bcur     = (int*)(ws + alloc(NBKT * 4));
    int*   bbase    = (int*)(ws + alloc(NBKT * 4));
    ushort_t* whi   = (ushort_t*)(ws + alloc(16384 * 2));
    ushort_t* wlo   = (ushort_t*)(ws + alloc(16384 * 2));
    ushort_t* w2hi  = (ushort_t*)(ws + alloc(4096 * 2));
    ushort_t* w2lo  = (ushort_t*)(ws + alloc(4096 * 2));
    uint_t* binned  = (uint_t*)(ws + alloc((size_t)NBKT * BCAP * 4));
    int*   csr      = (int*)(ws + alloc((size_t)E * 4));

    const int nbkt = (N + 511) / 512;  // 196 for N=100000

    hipMemsetAsync(bcur, 0, NBKT * 4, stream);
    k_prepW<<<64, 256, 0, stream>>>(W1, whi, wlo);
    k_prepW2<<<16, 256, 0, stream>>>(W2, w2hi, w2lo);
    k_bin<<<(E + 4095) / 4096, 256, 0, stream>>>(ei, bcur, binned, E);
    k_bktscan<<<1, 256, 0, stream>>>(bcur, bbase, rowstart, N, E);
    k_csr<<<nbkt, 256, 0, stream>>>(binned, bcur, bbase, csr, cnt, dinv, rowstart, N);
    k_gemm1ln<<<(N + 63) / 64, 256, 0, stream>>>(x, whi, wlo, b1, g1, be1, dinv, u0, N);

    ushort_t* bufs[2] = {ua, ub};
    const ushort_t* pin = u0;
    for (int k = 0; k < 10; ++k) {
        ushort_t* pout = bufs[k & 1];
        k_prop<<<(N + 3) / 4, 256, 0, stream>>>(pin, u0, pout, csr, rowstart, dinv, N);
        pin = pout;
    }
    k_final<<<(N + 63) / 64, 256, 0, stream>>>(pin, cnt, g2, be2, w2hi, w2lo, b2, out, N);
}